// Round 6
// baseline (285.838 us; speedup 1.0000x reference)
//
#include <hip/hip_runtime.h>
#include <math.h>

#define BB   16
#define RR   4096
#define NC   80          // foreground classes
#define KK   300
#define DD   100
#define CCAP 512         // per-(image,class) candidate cap (expected ~118, sigma ~11)
#define CAP  16384       // per-image kept-candidate cap (expected ~8800)
#define LCAP 48          // per-(block,class) local cap in kernel A
#define NW   5           // 5*64 = 320 >= KK bitmask words
#define PAD  (NW * 64)   // 320 padded box slots

typedef unsigned long long ull;

__device__ __forceinline__ float4 decode_box(const float4 pr, const float4 rg) {
    // shared by percls (NMS) and topd (output) -> bit-identical
    float dx = rg.x / 10.0f;
    float dy = rg.y / 10.0f;
    float dw = fminf(rg.z / 5.0f, 4.135166556742356f);
    float dh = fminf(rg.w / 5.0f, 4.135166556742356f);
    float w  = pr.z - pr.x + 1.0f;
    float h  = pr.w - pr.y + 1.0f;
    float cx = pr.x + 0.5f * w;
    float cy = pr.y + 0.5f * h;
    float pcx = dx * w + cx;
    float pcy = dy * h + cy;
    float pw  = expf(dw) * w;
    float ph  = expf(dh) * h;
    float x1 = pcx - 0.5f * pw;
    float y1 = pcy - 0.5f * ph;
    float x2 = pcx + 0.5f * pw - 1.0f;
    float y2 = pcy + 0.5f * ph - 1.0f;
    x1 = fminf(fmaxf(x1, 0.0f), 1332.0f);
    y1 = fminf(fmaxf(y1, 0.0f), 799.0f);
    x2 = fminf(fmaxf(x2, 0.0f), 1332.0f);
    y2 = fminf(fmaxf(y2, 0.0f), 799.0f);
    return make_float4(x1, y1, x2, y2);
}

// ---- Kernel A: LDS-staged coalesced softmax + block-aggregated candidate emit ----
__global__ __launch_bounds__(256) void softmax_cand_kernel(
        const float* __restrict__ logits,
        ull*         __restrict__ cand2,     // [BB*NC][CCAP]
        int*         __restrict__ cls_cnt) { // [BB*NC]
    __shared__ float tile[256 * 81];         // 82,944 B (82944 % 16 == 0 per block)
    __shared__ ull   lbuf[NC * LCAP];        // 30,720 B
    __shared__ int   lhist[NC];
    __shared__ int   gbase[NC];

    const int tid  = threadIdx.x;
    const int row0 = blockIdx.x * 256;
    const int b    = blockIdx.x >> 4;

    for (int i = tid; i < NC; i += 256) lhist[i] = 0;

    // coalesced float4 staging of 256 rows (20736 dwords = 5184 float4)
    const float4* src = (const float4*)(logits + (size_t)row0 * 81);
    float4*       dst = (float4*)tile;
    for (int i = tid; i < 5184; i += 256) dst[i] = src[i];
    __syncthreads();

    // this thread's row -> registers (conflict-free: 81*t mod 32 is 2-way)
    float v[81];
    #pragma unroll
    for (int c = 0; c < 81; ++c) v[c] = tile[tid * 81 + c];

    float m = -1e30f;
    #pragma unroll
    for (int c = 0; c < 81; ++c) m = fmaxf(m, v[c]);

    float s = 0.0f;
    #pragma unroll
    for (int c = 0; c < 81; ++c) { float e = expf(v[c] - m); v[c] = e; s += e; }

    const unsigned rlow = (unsigned)((row0 + tid) & 4095);
    #pragma unroll
    for (int c = 1; c < 81; ++c) {
        float p = v[c] / s;
        if (p > 0.05f) {
            int ci  = c - 1;
            int pos = atomicAdd(&lhist[ci], 1);
            if (pos < LCAP)
                lbuf[ci * LCAP + pos] =
                    ((ull)__float_as_uint(p) << 32) | (unsigned)(~rlow);
        }
    }
    __syncthreads();

    if (tid < NC) {
        int h = lhist[tid]; if (h > LCAP) h = LCAP;
        gbase[tid] = atomicAdd(&cls_cnt[b * NC + tid], h);
    }
    __syncthreads();

    for (int idx = tid; idx < NC * LCAP; idx += 256) {
        int ci = idx / LCAP, j = idx - ci * LCAP;
        int h  = lhist[ci]; if (h > LCAP) h = LCAP;
        if (j < h) {
            int pos = gbase[ci] + j;
            if (pos < CCAP)
                cand2[(size_t)(b * NC + ci) * CCAP + pos] = lbuf[idx];
        }
    }
}

// ---- Kernel B: ONE WAVE per (image,class): sort + decode + uniform-j bitmask NMS ----
__global__ __launch_bounds__(64) void percls_kernel(
        const ull*   __restrict__ cand2,
        const int*   __restrict__ cls_cnt,
        const float* __restrict__ box_reg,
        const float* __restrict__ proposals,
        ull*         __restrict__ img_keys,   // [BB][CAP]
        unsigned*    __restrict__ img_meta,   // [BB][CAP]  (ci<<12 | r)
        int*         __restrict__ g_cnt) {    // [BB]
    #pragma clang fp contract(off)
    __shared__ ull    keys[CCAP];
    __shared__ float4 bxy[PAD];
    __shared__ float  bar[PAD];

    const int bid = blockIdx.x;
    const int b   = bid / NC;
    const int ci  = bid % NC;
    const int tid = threadIdx.x;   // 0..63, single wave

    int M = cls_cnt[bid]; if (M > CCAP) M = CCAP;
    int sortN = 2; while (sortN < M) sortN <<= 1;

    for (int i = tid; i < sortN; i += 64)
        keys[i] = (i < M) ? cand2[(size_t)bid * CCAP + i] : 0ULL;
    __syncthreads();

    for (int k = 2; k <= sortN; k <<= 1) {
        for (int j = k >> 1; j > 0; j >>= 1) {
            for (int i = tid; i < sortN; i += 64) {
                int ixj = i ^ j;
                if (ixj > i) {
                    bool desc = ((i & k) == 0);
                    ull a = keys[i], c = keys[ixj];
                    if (desc ? (a < c) : (a > c)) { keys[i] = c; keys[ixj] = a; }
                }
            }
            __syncthreads();
        }
    }

    const int N = (M < KK) ? M : KK;

    for (int k2 = tid; k2 < PAD; k2 += 64) {
        if (k2 < N) {
            unsigned r = ~(unsigned)(keys[k2] & 0xFFFFFFFFu);
            size_t n = (size_t)b * RR + r;
            const float4 pr = *(const float4*)(proposals + n * 4);
            const float4 rg = *(const float4*)(box_reg + n * 324 + (size_t)(ci + 1) * 4);
            float4 bb = decode_box(pr, rg);
            bxy[k2] = bb;
            bar[k2] = (bb.z - bb.x + 1.0f) * (bb.w - bb.y + 1.0f);
        } else {
            bxy[k2] = make_float4(0.0f, 0.0f, 0.0f, 0.0f);
            bar[k2] = 0.0f;
        }
    }
    __syncthreads();

    // keep mask (wave-uniform), one bit per candidate
    ull keepw[NW];
    #pragma unroll
    for (int w = 0; w < NW; ++w) {
        int lo = w * 64;
        keepw[w] = (N >= lo + 64) ? ~0ULL : (N <= lo ? 0ULL : ((1ULL << (N - lo)) - 1ULL));
    }

    #pragma unroll
    for (int t = 0; t < NW; ++t) {
        if (t * 64 >= N) break;
        const int i = t * 64 + tid;          // this lane's row (may be >= N: masked below)
        const float4 a   = bxy[i];
        const float  aar = bar[i];
        ull sup[NW];
        #pragma unroll
        for (int w = 0; w < NW; ++w) {
            ull mword = 0ULL;
            if (w >= t && w * 64 < N) {
                // uniform j across lanes -> LDS broadcast reads; static bounds -> unroll/ILP
                #pragma unroll 4
                for (int jj = 0; jj < 64; ++jj) {
                    const int j = w * 64 + jj;
                    const float4 bb = bxy[j];
                    const float  ba = bar[j];
                    float ltx = fmaxf(a.x, bb.x);
                    float lty = fmaxf(a.y, bb.y);
                    float rbx = fminf(a.z, bb.z);
                    float rby = fminf(a.w, bb.w);
                    float iw  = fmaxf(rbx - ltx + 1.0f, 0.0f);
                    float ih  = fmaxf(rby - lty + 1.0f, 0.0f);
                    float inter = iw * ih;
                    float iou   = inter / ((aar + ba) - inter);
                    if ((j > i) && (j < N) && (iou > 0.5f)) mword |= 1ULL << jj;
                }
            }
            sup[w] = mword;
        }
        const int lmax = (N - t * 64 < 64) ? (N - t * 64) : 64;
        for (int l = 0; l < lmax; ++l) {
            if ((keepw[t] >> l) & 1ULL) {
                #pragma unroll
                for (int w = 0; w < NW; ++w) {
                    if (w >= t && w * 64 < N)
                        keepw[w] &= ~__shfl(sup[w], l);
                }
            }
        }
    }

    // append kept entries (key is a total order -> append order is irrelevant)
    #pragma unroll
    for (int t = 0; t < NW; ++t) {
        if (t * 64 >= N) break;
        int k2 = t * 64 + tid;
        if (k2 < N && ((keepw[t] >> tid) & 1ULL)) {
            int pos = atomicAdd(&g_cnt[b], 1);
            if (pos < CAP) {
                unsigned r  = ~(unsigned)(keys[k2] & 0xFFFFFFFFu);
                unsigned fi = (unsigned)(ci * KK + k2);
                img_keys[(size_t)b * CAP + pos] =
                    (keys[k2] & 0xFFFFFFFF00000000ULL) | (unsigned)(~fi);
                img_meta[(size_t)b * CAP + pos] = ((unsigned)ci << 12) | (r & 4095u);
            }
        }
    }
}

// ---- Kernel C: per-image exact top-100 (register-resident) + re-decode + output ----
__global__ __launch_bounds__(256) void topd_kernel(
        const ull*      __restrict__ img_keys,
        const unsigned* __restrict__ img_meta,
        const int*      __restrict__ g_cnt,
        const float*    __restrict__ box_reg,
        const float*    __restrict__ proposals,
        float*          __restrict__ out) {
    #pragma clang fp contract(off)
    __shared__ unsigned wred[8];
    __shared__ ull      pk[256];
    __shared__ int      ps[256];
    __shared__ int      sh_cnt;

    const int b   = blockIdx.x;
    const int tid = threadIdx.x;
    int M = g_cnt[b]; if (M > CAP) M = CAP;
    const ull* kp = img_keys + (size_t)b * CAP;

    // stage this thread's score bits into registers (CAP/256 = 64 slots max)
    unsigned sreg[64];
    #pragma unroll
    for (int r = 0; r < 64; ++r) {
        int i = tid + r * 256;
        sreg[r] = (i < M) ? ((const unsigned*)kp)[2 * i + 1] : 0u;
    }

    // largest T with count(>= T) >= DD  (scores in (0.05, 1.0])
    unsigned lo = 0x3D4CCCCDu;        // 0.05f
    unsigned hi = 0x40000000u;        // 2.0f
    int par = 0;
    while (hi - lo > 1u) {
        unsigned mid = lo + ((hi - lo) >> 1);
        int c = 0;
        #pragma unroll
        for (int r = 0; r < 64; ++r) c += (sreg[r] >= mid) ? 1 : 0;
        for (int off = 32; off; off >>= 1) c += __shfl_down(c, off);
        if ((tid & 63) == 0) wred[par * 4 + (tid >> 6)] = (unsigned)c;
        __syncthreads();
        int total = (int)(wred[par * 4] + wred[par * 4 + 1] +
                          wred[par * 4 + 2] + wred[par * 4 + 3]);
        if (total >= DD) lo = mid; else hi = mid;
        par ^= 1;
    }
    const unsigned T = lo;

    if (tid == 0) sh_cnt = 0;
    __syncthreads();
    #pragma unroll
    for (int r = 0; r < 64; ++r) {
        int i = tid + r * 256;
        if (sreg[r] >= T && i < M) {
            int p = atomicAdd(&sh_cnt, 1);
            if (p < 256) { pk[p] = kp[i]; ps[p] = i; }
        }
    }
    __syncthreads();
    int ngath = sh_cnt; if (ngath > 256) ngath = 256;   // expected ~100-101
    const int sortN = (ngath <= 128) ? 128 : 256;
    for (int i = tid; i < sortN; i += 256) if (i >= ngath) { pk[i] = 0ULL; ps[i] = -1; }
    __syncthreads();

    for (int k = 2; k <= sortN; k <<= 1) {
        for (int j = k >> 1; j > 0; j >>= 1) {
            for (int i = tid; i < sortN; i += 256) {
                int ixj = i ^ j;
                if (ixj > i) {
                    bool desc = ((i & k) == 0);
                    ull a = pk[i], c = pk[ixj];
                    if (desc ? (a < c) : (a > c)) {
                        pk[i] = c; pk[ixj] = a;
                        int t = ps[i]; ps[i] = ps[ixj]; ps[ixj] = t;
                    }
                }
            }
            __syncthreads();
        }
    }

    if (tid < DD) {
        float s; float4 bb; int label;
        if (tid < ngath) {
            ull key = pk[tid];
            unsigned fi   = ~(unsigned)(key & 0xFFFFFFFFu);
            unsigned meta = img_meta[(size_t)b * CAP + ps[tid]];
            unsigned r    = meta & 4095u;
            unsigned ci   = meta >> 12;
            s  = __uint_as_float((unsigned)(key >> 32));
            size_t n = (size_t)b * RR + r;
            const float4 pr = *(const float4*)(proposals + n * 4);
            const float4 rg = *(const float4*)(box_reg + n * 324 + (size_t)(ci + 1) * 4);
            bb = decode_box(pr, rg);          // bit-identical to percls's decode
            label = (int)(fi / KK) + 1;
        } else {
            s = -1.0f; bb = make_float4(0.0f, 0.0f, 0.0f, 0.0f); label = 0;
        }
        out[(size_t)(b * DD + tid) * 4 + 0] = bb.x;
        out[(size_t)(b * DD + tid) * 4 + 1] = bb.y;
        out[(size_t)(b * DD + tid) * 4 + 2] = bb.z;
        out[(size_t)(b * DD + tid) * 4 + 3] = bb.w;
        out[(size_t)BB * DD * 4 + b * DD + tid] = s;
        out[(size_t)BB * DD * 4 + BB * DD + b * DD + tid] = (float)label;
    }
}

extern "C" void kernel_launch(void* const* d_in, const int* in_sizes, int n_in,
                              void* d_out, int out_size, void* d_ws, size_t ws_size,
                              hipStream_t stream) {
    const float* logits    = (const float*)d_in[0];   // [B*R, 81]
    const float* box_reg   = (const float*)d_in[1];   // [B*R, 324]
    const float* proposals = (const float*)d_in[2];   // [B*R, 4]
    float* out = (float*)d_out;

    char* ws = (char*)d_ws;
    int*      cls_cnt  = (int*)ws;                    //     5,120 B
    int*      g_cnt    = (int*)(ws + 5120);           //        64 B
    ull*      cand2    = (ull*)(ws + 5184);           // 5,242,880 B
    ull*      img_keys = (ull*)(ws + 5248064);        // 2,097,152 B
    unsigned* img_meta = (unsigned*)(ws + 7345216);   // 1,048,576 B

    hipMemsetAsync(ws, 0, 5184, stream);
    softmax_cand_kernel<<<(BB * RR) / 256, 256, 0, stream>>>(logits, cand2, cls_cnt);
    percls_kernel<<<BB * NC, 64, 0, stream>>>(cand2, cls_cnt, box_reg, proposals,
                                              img_keys, img_meta, g_cnt);
    topd_kernel<<<BB, 256, 0, stream>>>(img_keys, img_meta, g_cnt,
                                        box_reg, proposals, out);
}

// Round 7
// 251.764 us; speedup vs baseline: 1.1353x; 1.1353x over previous
//
#include <hip/hip_runtime.h>
#include <math.h>

#define BB   16
#define RR   4096
#define NC   80          // foreground classes
#define KK   300
#define DD   100
#define CCAP 512         // per-(image,class) candidate cap (expected ~118, sigma ~11)
#define CAP  16384       // per-image kept-candidate cap (expected ~8800)
#define LCAP 48          // per-(block,class) local cap in kernel A
#define NW   5           // 5*64 = 320 >= KK bitmask words
#define PAD  (NW * 64)   // 320 padded box slots
#define HBINS 1280       // topd histogram bins (used: 1128)
#define HPT   5          // bins per thread (1280/256)
#define BIN0  0x7A99u    // (0x3D4CCCCD >> 15): bin of score==0.05f

typedef unsigned long long ull;

__device__ __forceinline__ float4 decode_box(const float4 pr, const float4 rg) {
    // shared by percls (NMS) and topd (output) -> identical codegen, bit-identical
    float dx = rg.x / 10.0f;
    float dy = rg.y / 10.0f;
    float dw = fminf(rg.z / 5.0f, 4.135166556742356f);
    float dh = fminf(rg.w / 5.0f, 4.135166556742356f);
    float w  = pr.z - pr.x + 1.0f;
    float h  = pr.w - pr.y + 1.0f;
    float cx = pr.x + 0.5f * w;
    float cy = pr.y + 0.5f * h;
    float pcx = dx * w + cx;
    float pcy = dy * h + cy;
    float pw  = expf(dw) * w;
    float ph  = expf(dh) * h;
    float x1 = pcx - 0.5f * pw;
    float y1 = pcy - 0.5f * ph;
    float x2 = pcx + 0.5f * pw - 1.0f;
    float y2 = pcy + 0.5f * ph - 1.0f;
    x1 = fminf(fmaxf(x1, 0.0f), 1332.0f);
    y1 = fminf(fmaxf(y1, 0.0f), 799.0f);
    x2 = fminf(fmaxf(x2, 0.0f), 1332.0f);
    y2 = fminf(fmaxf(y2, 0.0f), 799.0f);
    return make_float4(x1, y1, x2, y2);
}

// ---- Kernel A: LDS-staged coalesced softmax + block-aggregated candidate emit ----
__global__ __launch_bounds__(256) void softmax_cand_kernel(
        const float* __restrict__ logits,
        ull*         __restrict__ cand2,     // [BB*NC][CCAP]
        int*         __restrict__ cls_cnt) { // [BB*NC]
    __shared__ float tile[256 * 81];
    __shared__ ull   lbuf[NC * LCAP];
    __shared__ int   lhist[NC];
    __shared__ int   gbase[NC];

    const int tid  = threadIdx.x;
    const int row0 = blockIdx.x * 256;
    const int b    = blockIdx.x >> 4;

    for (int i = tid; i < NC; i += 256) lhist[i] = 0;

    const float4* src = (const float4*)(logits + (size_t)row0 * 81);
    float4*       dst = (float4*)tile;
    for (int i = tid; i < 5184; i += 256) dst[i] = src[i];
    __syncthreads();

    float v[81];
    #pragma unroll
    for (int c = 0; c < 81; ++c) v[c] = tile[tid * 81 + c];

    float m = -1e30f;
    #pragma unroll
    for (int c = 0; c < 81; ++c) m = fmaxf(m, v[c]);

    float s = 0.0f;
    #pragma unroll
    for (int c = 0; c < 81; ++c) { float e = expf(v[c] - m); v[c] = e; s += e; }

    const unsigned rlow = (unsigned)((row0 + tid) & 4095);
    #pragma unroll
    for (int c = 1; c < 81; ++c) {
        float p = v[c] / s;
        if (p > 0.05f) {
            int ci  = c - 1;
            int pos = atomicAdd(&lhist[ci], 1);
            if (pos < LCAP)
                lbuf[ci * LCAP + pos] =
                    ((ull)__float_as_uint(p) << 32) | (unsigned)(~rlow);
        }
    }
    __syncthreads();

    if (tid < NC) {
        int h = lhist[tid]; if (h > LCAP) h = LCAP;
        gbase[tid] = atomicAdd(&cls_cnt[b * NC + tid], h);
    }
    __syncthreads();

    for (int idx = tid; idx < NC * LCAP; idx += 256) {
        int ci = idx / LCAP, j = idx - ci * LCAP;
        int h  = lhist[ci]; if (h > LCAP) h = LCAP;
        if (j < h) {
            int pos = gbase[ci] + j;
            if (pos < CCAP)
                cand2[(size_t)(b * NC + ci) * CCAP + pos] = lbuf[idx];
        }
    }
}

// ---- Kernel B: ONE WAVE per (image,class): sort + decode + bitmask NMS ----
__global__ __launch_bounds__(64) void percls_kernel(
        const ull*   __restrict__ cand2,
        const int*   __restrict__ cls_cnt,
        const float* __restrict__ box_reg,
        const float* __restrict__ proposals,
        ull*         __restrict__ img_keys,   // [BB][CAP]
        unsigned*    __restrict__ img_meta,   // [BB][CAP]  (ci<<12 | r)
        int*         __restrict__ g_cnt) {    // [BB]
    #pragma clang fp contract(off)
    __shared__ ull   keys[CCAP];
    __shared__ float bx1[PAD], by1[PAD], bx2[PAD], by2[PAD], bar[PAD];

    const int bid = blockIdx.x;
    const int b   = bid / NC;
    const int ci  = bid % NC;
    const int tid = threadIdx.x;   // 0..63, single wave

    int M = cls_cnt[bid]; if (M > CCAP) M = CCAP;
    int sortN = 2; while (sortN < M) sortN <<= 1;

    for (int i = tid; i < sortN; i += 64)
        keys[i] = (i < M) ? cand2[(size_t)bid * CCAP + i] : 0ULL;
    __syncthreads();

    for (int k = 2; k <= sortN; k <<= 1) {
        for (int j = k >> 1; j > 0; j >>= 1) {
            for (int i = tid; i < sortN; i += 64) {
                int ixj = i ^ j;
                if (ixj > i) {
                    bool desc = ((i & k) == 0);
                    ull a = keys[i], c = keys[ixj];
                    if (desc ? (a < c) : (a > c)) { keys[i] = c; keys[ixj] = a; }
                }
            }
            __syncthreads();
        }
    }

    const int N = (M < KK) ? M : KK;

    for (int k2 = tid; k2 < PAD; k2 += 64) {
        if (k2 < N) {
            unsigned r = ~(unsigned)(keys[k2] & 0xFFFFFFFFu);
            size_t n = (size_t)b * RR + r;
            const float4 pr = *(const float4*)(proposals + n * 4);
            const float4 rg = *(const float4*)(box_reg + n * 324 + (size_t)(ci + 1) * 4);
            float4 bb = decode_box(pr, rg);
            bx1[k2] = bb.x; by1[k2] = bb.y; bx2[k2] = bb.z; by2[k2] = bb.w;
            bar[k2] = (bb.z - bb.x + 1.0f) * (bb.w - bb.y + 1.0f);
        } else {
            bx1[k2] = 0.0f; by1[k2] = 0.0f; bx2[k2] = 0.0f; by2[k2] = 0.0f;
            bar[k2] = 0.0f;
        }
    }
    __syncthreads();

    // keep mask (wave-uniform), one bit per candidate (<N only)
    ull keepw[NW];
    #pragma unroll
    for (int w = 0; w < NW; ++w) {
        int lo = w * 64;
        keepw[w] = (N >= lo + 64) ? ~0ULL : (N <= lo ? 0ULL : ((1ULL << (N - lo)) - 1ULL));
    }

    // per-lane suppression rows (divergent j>i triangle: minimal work), shfl resolve
    #pragma unroll
    for (int t = 0; t < NW; ++t) {
        if (t * 64 >= N) break;
        const int i = t * 64 + tid;
        const float ax1 = bx1[i], ay1 = by1[i], ax2 = bx2[i], ay2 = by2[i], aar = bar[i];
        ull sup[NW];
        #pragma unroll
        for (int w = 0; w < NW; ++w) {
            ull mword = 0ULL;
            if (w >= t && w * 64 < N) {
                int jlo = w * 64; if (jlo < i + 1) jlo = i + 1;
                int jhi = w * 64 + 64; if (jhi > N) jhi = N;
                for (int j = jlo; j < jhi; ++j) {
                    float ltx = fmaxf(ax1, bx1[j]);
                    float lty = fmaxf(ay1, by1[j]);
                    float rbx = fminf(ax2, bx2[j]);
                    float rby = fminf(ay2, by2[j]);
                    float iw  = fmaxf(rbx - ltx + 1.0f, 0.0f);
                    float ih  = fmaxf(rby - lty + 1.0f, 0.0f);
                    float inter = iw * ih;
                    float iou   = inter / ((aar + bar[j]) - inter);
                    if (iou > 0.5f) mword |= 1ULL << (j - w * 64);
                }
            }
            sup[w] = mword;
        }
        const int lmax = (N - t * 64 < 64) ? (N - t * 64) : 64;
        for (int l = 0; l < lmax; ++l) {
            if ((keepw[t] >> l) & 1ULL) {
                #pragma unroll
                for (int w = 0; w < NW; ++w) {
                    if (w >= t && w * 64 < N)
                        keepw[w] &= ~__shfl(sup[w], l);
                }
            }
        }
    }

    // append kept entries: ONE global atomic per block, popcll-rank offsets
    int total = 0;
    #pragma unroll
    for (int w = 0; w < NW; ++w) total += __popcll(keepw[w]);
    int base0 = 0;
    if (tid == 0) base0 = atomicAdd(&g_cnt[b], total);
    base0 = __shfl(base0, 0);

    int acc = 0;
    #pragma unroll
    for (int w = 0; w < NW; ++w) {
        if (w * 64 < N) {
            const ull km = keepw[w];
            const int k2 = w * 64 + tid;
            if ((km >> tid) & 1ULL) {
                int rank = __popcll(km & ((1ULL << tid) - 1ULL));
                int pos  = base0 + acc + rank;
                if (pos < CAP) {
                    unsigned r  = ~(unsigned)(keys[k2] & 0xFFFFFFFFu);
                    unsigned fi = (unsigned)(ci * KK + k2);
                    img_keys[(size_t)b * CAP + pos] =
                        (keys[k2] & 0xFFFFFFFF00000000ULL) | (unsigned)(~fi);
                    img_meta[(size_t)b * CAP + pos] = ((unsigned)ci << 12) | (r & 4095u);
                }
            }
            acc += __popcll(km);
        }
    }
}

// ---- Kernel C: per-image exact top-100 via one-pass histogram select ----
__global__ __launch_bounds__(256) void topd_kernel(
        const ull*      __restrict__ img_keys,
        const unsigned* __restrict__ img_meta,
        const int*      __restrict__ g_cnt,
        const float*    __restrict__ box_reg,
        const float*    __restrict__ proposals,
        float*          __restrict__ out) {
    __shared__ int  hist[HBINS];
    __shared__ int  suf[256];
    __shared__ ull  pk[512];
    __shared__ int  ps[512];
    __shared__ int  sh_cnt, sh_tb;

    const int b   = blockIdx.x;
    const int tid = threadIdx.x;
    int M = g_cnt[b]; if (M > CAP) M = CAP;
    const ull* kp = img_keys + (size_t)b * CAP;

    #pragma unroll
    for (int r = 0; r < HPT; ++r) hist[tid + r * 256] = 0;
    if (tid == 0) { sh_cnt = 0; sh_tb = 0; }
    __syncthreads();

    // 1) histogram on score-bits >> 15 (monotone map; scores in (0.05, 1.0])
    for (int i = tid; i < M; i += 256) {
        unsigned k = (unsigned)(kp[i] >> 32);
        int bin = (int)((k >> 15) - BIN0);
        bin = (bin < 0) ? 0 : (bin >= HBINS ? HBINS - 1 : bin);
        atomicAdd(&hist[bin], 1);
    }
    __syncthreads();

    // 2) suffix scan: thread t owns bins [5t, 5t+5)
    int tot = 0;
    #pragma unroll
    for (int r = 0; r < HPT; ++r) tot += hist[tid * HPT + r];
    suf[tid] = tot;
    __syncthreads();
    for (int off = 1; off < 256; off <<= 1) {
        int add = (tid + off < 256) ? suf[tid + off] : 0;
        __syncthreads();
        suf[tid] += add;
        __syncthreads();
    }
    // 3) threshold bin: largest bin j with count(>= bin j) >= DD
    {
        int cum = suf[tid] - tot;                 // count strictly above own chunk
        #pragma unroll
        for (int jj = HPT - 1; jj >= 0; --jj) {
            int j    = tid * HPT + jj;
            int prev = cum;                       // cum(j+1)
            cum += hist[j];                       // cum(j)
            if (cum >= DD && prev < DD) sh_tb = j;
        }
    }
    __syncthreads();
    const unsigned keyLo = ((unsigned)sh_tb + BIN0) << 15;

    // 4) gather all candidates with score bits >= keyLo (expected ~100-130)
    for (int i = tid; i < M; i += 256) {
        ull key = kp[i];
        if ((unsigned)(key >> 32) >= keyLo) {
            int p = atomicAdd(&sh_cnt, 1);
            if (p < 512) { pk[p] = key; ps[p] = i; }
        }
    }
    __syncthreads();
    int ngath = sh_cnt; if (ngath > 512) ngath = 512;
    const int sortN = (ngath <= 128) ? 128 : (ngath <= 256) ? 256 : 512;
    for (int i = tid; i < sortN; i += 256) if (i >= ngath) { pk[i] = 0ULL; ps[i] = -1; }
    __syncthreads();

    // 5) bitonic sort desc by key (score, then lower flat idx)
    for (int k = 2; k <= sortN; k <<= 1) {
        for (int j = k >> 1; j > 0; j >>= 1) {
            for (int i = tid; i < sortN; i += 256) {
                int ixj = i ^ j;
                if (ixj > i) {
                    bool desc = ((i & k) == 0);
                    ull a = pk[i], c = pk[ixj];
                    if (desc ? (a < c) : (a > c)) {
                        pk[i] = c; pk[ixj] = a;
                        int t = ps[i]; ps[i] = ps[ixj]; ps[ixj] = t;
                    }
                }
            }
            __syncthreads();
        }
    }

    // 6) emit top-100 (boxes re-decoded bit-identically)
    if (tid < DD) {
        float s; float4 bb; int label;
        if (tid < ngath) {
            ull key = pk[tid];
            unsigned fi   = ~(unsigned)(key & 0xFFFFFFFFu);
            unsigned meta = img_meta[(size_t)b * CAP + ps[tid]];
            unsigned r    = meta & 4095u;
            unsigned ci   = meta >> 12;
            s  = __uint_as_float((unsigned)(key >> 32));
            size_t n = (size_t)b * RR + r;
            const float4 pr = *(const float4*)(proposals + n * 4);
            const float4 rg = *(const float4*)(box_reg + n * 324 + (size_t)(ci + 1) * 4);
            bb = decode_box(pr, rg);
            label = (int)(fi / KK) + 1;
        } else {
            s = -1.0f; bb = make_float4(0.0f, 0.0f, 0.0f, 0.0f); label = 0;
        }
        out[(size_t)(b * DD + tid) * 4 + 0] = bb.x;
        out[(size_t)(b * DD + tid) * 4 + 1] = bb.y;
        out[(size_t)(b * DD + tid) * 4 + 2] = bb.z;
        out[(size_t)(b * DD + tid) * 4 + 3] = bb.w;
        out[(size_t)BB * DD * 4 + b * DD + tid] = s;
        out[(size_t)BB * DD * 4 + BB * DD + b * DD + tid] = (float)label;
    }
}

extern "C" void kernel_launch(void* const* d_in, const int* in_sizes, int n_in,
                              void* d_out, int out_size, void* d_ws, size_t ws_size,
                              hipStream_t stream) {
    const float* logits    = (const float*)d_in[0];   // [B*R, 81]
    const float* box_reg   = (const float*)d_in[1];   // [B*R, 324]
    const float* proposals = (const float*)d_in[2];   // [B*R, 4]
    float* out = (float*)d_out;

    char* ws = (char*)d_ws;
    int*      cls_cnt  = (int*)ws;                    //     5,120 B
    int*      g_cnt    = (int*)(ws + 5120);           //        64 B
    ull*      cand2    = (ull*)(ws + 5184);           // 5,242,880 B
    ull*      img_keys = (ull*)(ws + 5248064);        // 2,097,152 B
    unsigned* img_meta = (unsigned*)(ws + 7345216);   // 1,048,576 B

    hipMemsetAsync(ws, 0, 5184, stream);
    softmax_cand_kernel<<<(BB * RR) / 256, 256, 0, stream>>>(logits, cand2, cls_cnt);
    percls_kernel<<<BB * NC, 64, 0, stream>>>(cand2, cls_cnt, box_reg, proposals,
                                              img_keys, img_meta, g_cnt);
    topd_kernel<<<BB, 256, 0, stream>>>(img_keys, img_meta, g_cnt,
                                        box_reg, proposals, out);
}

// Round 8
// 224.033 us; speedup vs baseline: 1.2759x; 1.1238x over previous
//
#include <hip/hip_runtime.h>
#include <math.h>

#define BB   16
#define RR   4096
#define NC   80          // foreground classes
#define KK   300
#define DD   100
#define CCAP 512         // per-(image,class) candidate cap (expected ~118, sigma ~11)
#define CAP  16384       // per-image kept-candidate cap (expected ~8800)
#define LCAP 48          // per-(block,class) local cap in kernel A
#define NW   5           // 5*64 = 320 >= KK bitmask words
#define PAD  (NW * 64)   // 320 padded box slots
#define TPB  4           // percls tasks (waves) per block
#define HBINS 1280       // topd histogram bins (used: 1128)
#define HPT   5          // bins per scan-thread (1280/256)
#define BIN0  0x7A99u    // (0x3D4CCCCD >> 15): bin of score==0.05f

typedef unsigned long long ull;

// wave-local "barrier": drain LDS ops + compiler memory fence (single-wave tasks)
__device__ __forceinline__ void wsync() {
    asm volatile("s_waitcnt lgkmcnt(0)" ::: "memory");
}

__device__ __forceinline__ float4 decode_box(const float4 pr, const float4 rg) {
    float dx = rg.x / 10.0f;
    float dy = rg.y / 10.0f;
    float dw = fminf(rg.z / 5.0f, 4.135166556742356f);
    float dh = fminf(rg.w / 5.0f, 4.135166556742356f);
    float w  = pr.z - pr.x + 1.0f;
    float h  = pr.w - pr.y + 1.0f;
    float cx = pr.x + 0.5f * w;
    float cy = pr.y + 0.5f * h;
    float pcx = dx * w + cx;
    float pcy = dy * h + cy;
    float pw  = expf(dw) * w;
    float ph  = expf(dh) * h;
    float x1 = pcx - 0.5f * pw;
    float y1 = pcy - 0.5f * ph;
    float x2 = pcx + 0.5f * pw - 1.0f;
    float y2 = pcy + 0.5f * ph - 1.0f;
    x1 = fminf(fmaxf(x1, 0.0f), 1332.0f);
    y1 = fminf(fmaxf(y1, 0.0f), 799.0f);
    x2 = fminf(fmaxf(x2, 0.0f), 1332.0f);
    y2 = fminf(fmaxf(y2, 0.0f), 799.0f);
    return make_float4(x1, y1, x2, y2);
}

// ---- Kernel A: LDS-staged coalesced softmax + block-aggregated candidate emit ----
__global__ __launch_bounds__(256) void softmax_cand_kernel(
        const float* __restrict__ logits,
        ull*         __restrict__ cand2,     // [BB*NC][CCAP]
        int*         __restrict__ cls_cnt) { // [BB*NC]
    __shared__ float tile[256 * 81];
    __shared__ ull   lbuf[NC * LCAP];
    __shared__ int   lhist[NC];
    __shared__ int   gbase[NC];

    const int tid  = threadIdx.x;
    const int row0 = blockIdx.x * 256;
    const int b    = blockIdx.x >> 4;

    for (int i = tid; i < NC; i += 256) lhist[i] = 0;

    const float4* src = (const float4*)(logits + (size_t)row0 * 81);
    float4*       dst = (float4*)tile;
    for (int i = tid; i < 5184; i += 256) dst[i] = src[i];
    __syncthreads();

    float v[81];
    #pragma unroll
    for (int c = 0; c < 81; ++c) v[c] = tile[tid * 81 + c];

    float m = -1e30f;
    #pragma unroll
    for (int c = 0; c < 81; ++c) m = fmaxf(m, v[c]);

    float s = 0.0f;
    #pragma unroll
    for (int c = 0; c < 81; ++c) { float e = expf(v[c] - m); v[c] = e; s += e; }

    const unsigned rlow = (unsigned)((row0 + tid) & 4095);
    #pragma unroll
    for (int c = 1; c < 81; ++c) {
        float p = v[c] / s;
        if (p > 0.05f) {
            int ci  = c - 1;
            int pos = atomicAdd(&lhist[ci], 1);
            if (pos < LCAP)
                lbuf[ci * LCAP + pos] =
                    ((ull)__float_as_uint(p) << 32) | (unsigned)(~rlow);
        }
    }
    __syncthreads();

    if (tid < NC) {
        int h = lhist[tid]; if (h > LCAP) h = LCAP;
        gbase[tid] = atomicAdd(&cls_cnt[b * NC + tid], h);
    }
    __syncthreads();

    for (int idx = tid; idx < NC * LCAP; idx += 256) {
        int ci = idx / LCAP, j = idx - ci * LCAP;
        int h  = lhist[ci]; if (h > LCAP) h = LCAP;
        if (j < h) {
            int pos = gbase[ci] + j;
            if (pos < CCAP)
                cand2[(size_t)(b * NC + ci) * CCAP + pos] = lbuf[idx];
        }
    }
}

// ---- Kernel B: 4 waves/block, ONE WAVE per (image,class), no block barriers ----
__global__ __launch_bounds__(256) void percls_kernel(
        const ull*   __restrict__ cand2,
        const int*   __restrict__ cls_cnt,
        const float* __restrict__ box_reg,
        const float* __restrict__ proposals,
        ull*         __restrict__ img_keys,   // [BB][CAP]
        unsigned*    __restrict__ img_meta,   // [BB][CAP]  (ci<<12 | r)
        int*         __restrict__ g_cnt) {    // [BB]
    #pragma clang fp contract(off)
    __shared__ ull   keys[TPB][CCAP];                  // 16,384 B
    __shared__ float bx1[TPB][PAD], by1[TPB][PAD],     // 25,600 B total boxes
                     bx2[TPB][PAD], by2[TPB][PAD], bar[TPB][PAD];

    const int wave = threadIdx.x >> 6;
    const int lane = threadIdx.x & 63;
    const int bid  = blockIdx.x * TPB + wave;   // 0..1279
    const int b    = bid / NC;
    const int ci   = bid % NC;

    int M = cls_cnt[bid]; if (M > CCAP) M = CCAP;
    int sortN = 2; while (sortN < M) sortN <<= 1;

    for (int i = lane; i < sortN; i += 64)
        keys[wave][i] = (i < M) ? cand2[(size_t)bid * CCAP + i] : 0ULL;
    wsync();

    for (int k = 2; k <= sortN; k <<= 1) {
        for (int j = k >> 1; j > 0; j >>= 1) {
            for (int i = lane; i < sortN; i += 64) {
                int ixj = i ^ j;
                if (ixj > i) {
                    bool desc = ((i & k) == 0);
                    ull a = keys[wave][i], c = keys[wave][ixj];
                    if (desc ? (a < c) : (a > c)) { keys[wave][i] = c; keys[wave][ixj] = a; }
                }
            }
            wsync();
        }
    }

    const int N = (M < KK) ? M : KK;

    for (int k2 = lane; k2 < PAD; k2 += 64) {
        if (k2 < N) {
            unsigned r = ~(unsigned)(keys[wave][k2] & 0xFFFFFFFFu);
            size_t n = (size_t)b * RR + r;
            const float4 pr = *(const float4*)(proposals + n * 4);
            const float4 rg = *(const float4*)(box_reg + n * 324 + (size_t)(ci + 1) * 4);
            float4 bb = decode_box(pr, rg);
            bx1[wave][k2] = bb.x; by1[wave][k2] = bb.y;
            bx2[wave][k2] = bb.z; by2[wave][k2] = bb.w;
            bar[wave][k2] = (bb.z - bb.x + 1.0f) * (bb.w - bb.y + 1.0f);
        } else {
            bx1[wave][k2] = 0.0f; by1[wave][k2] = 0.0f;
            bx2[wave][k2] = 0.0f; by2[wave][k2] = 0.0f;
            bar[wave][k2] = 0.0f;
        }
    }
    wsync();

    // keep mask (wave-uniform), one bit per candidate (<N only)
    ull keepw[NW];
    #pragma unroll
    for (int w = 0; w < NW; ++w) {
        int lo = w * 64;
        keepw[w] = (N >= lo + 64) ? ~0ULL : (N <= lo ? 0ULL : ((1ULL << (N - lo)) - 1ULL));
    }

    #pragma unroll
    for (int t = 0; t < NW; ++t) {
        if (t * 64 >= N) break;
        const int i = t * 64 + lane;
        const float ax1 = bx1[wave][i], ay1 = by1[wave][i],
                    ax2 = bx2[wave][i], ay2 = by2[wave][i], aar = bar[wave][i];
        ull sup[NW];
        #pragma unroll
        for (int w = 0; w < NW; ++w) {
            ull mword = 0ULL;
            if (w >= t && w * 64 < N) {
                int jlo = w * 64; if (jlo < i + 1) jlo = i + 1;
                int jhi = w * 64 + 64; if (jhi > N) jhi = N;
                for (int j = jlo; j < jhi; ++j) {
                    float ltx = fmaxf(ax1, bx1[wave][j]);
                    float lty = fmaxf(ay1, by1[wave][j]);
                    float rbx = fminf(ax2, bx2[wave][j]);
                    float rby = fminf(ay2, by2[wave][j]);
                    float iw  = fmaxf(rbx - ltx + 1.0f, 0.0f);
                    float ih  = fmaxf(rby - lty + 1.0f, 0.0f);
                    float inter = iw * ih;
                    float iou   = inter / ((aar + bar[wave][j]) - inter);
                    if (iou > 0.5f) mword |= 1ULL << (j - w * 64);
                }
            }
            sup[w] = mword;
        }
        // only leaders with a non-empty suppression row matter
        ull rowany = 0ULL;
        #pragma unroll
        for (int w = 0; w < NW; ++w) rowany |= sup[w];
        const ull act = __ballot(rowany != 0ULL);

        ull mloop = keepw[t] & act;
        while (mloop) {
            int l = __builtin_ctzll(mloop);
            if ((keepw[t] >> l) & 1ULL) {
                #pragma unroll
                for (int w = 0; w < NW; ++w) {
                    if (w >= t && w * 64 < N)
                        keepw[w] &= ~__shfl(sup[w], l);
                }
            }
            ull below = (l >= 63) ? ~0ULL : ((1ULL << (l + 1)) - 1ULL);
            mloop = keepw[t] & act & ~below;
        }
    }

    // append: ONE global atomic per wave, popcll-rank offsets
    int total = 0;
    #pragma unroll
    for (int w = 0; w < NW; ++w) total += __popcll(keepw[w]);
    int base0 = 0;
    if (lane == 0) base0 = atomicAdd(&g_cnt[b], total);
    base0 = __shfl(base0, 0);

    int acc = 0;
    #pragma unroll
    for (int w = 0; w < NW; ++w) {
        if (w * 64 < N) {
            const ull km = keepw[w];
            const int k2 = w * 64 + lane;
            if ((km >> lane) & 1ULL) {
                int rank = __popcll(km & ((1ULL << lane) - 1ULL));
                int pos  = base0 + acc + rank;
                if (pos < CAP) {
                    unsigned r  = ~(unsigned)(keys[wave][k2] & 0xFFFFFFFFu);
                    unsigned fi = (unsigned)(ci * KK + k2);
                    img_keys[(size_t)b * CAP + pos] =
                        (keys[wave][k2] & 0xFFFFFFFF00000000ULL) | (unsigned)(~fi);
                    img_meta[(size_t)b * CAP + pos] = ((unsigned)ci << 12) | (r & 4095u);
                }
            }
            acc += __popcll(km);
        }
    }
}

// ---- Kernel C: per-image exact top-100 via one-pass histogram select (1024 thr) ----
__global__ __launch_bounds__(1024) void topd_kernel(
        const ull*      __restrict__ img_keys,
        const unsigned* __restrict__ img_meta,
        const int*      __restrict__ g_cnt,
        const float*    __restrict__ box_reg,
        const float*    __restrict__ proposals,
        float*          __restrict__ out) {
    __shared__ int  hist[HBINS];
    __shared__ int  suf[256];
    __shared__ ull  pk[512];
    __shared__ int  ps[512];
    __shared__ int  sh_cnt, sh_tb;

    const int b   = blockIdx.x;
    const int tid = threadIdx.x;
    int M = g_cnt[b]; if (M > CAP) M = CAP;
    const ull* kp = img_keys + (size_t)b * CAP;

    for (int i = tid; i < HBINS; i += 1024) hist[i] = 0;
    if (tid == 0) { sh_cnt = 0; sh_tb = 0; }
    __syncthreads();

    // 1) histogram on score-bits >> 15 (monotone map; scores in (0.05, 1.0])
    for (int i = tid; i < M; i += 1024) {
        unsigned k = (unsigned)(kp[i] >> 32);
        int bin = (int)((k >> 15) - BIN0);
        bin = (bin < 0) ? 0 : (bin >= HBINS ? HBINS - 1 : bin);
        atomicAdd(&hist[bin], 1);
    }
    __syncthreads();

    // 2) suffix scan over 256 chunks (thread t owns bins [5t, 5t+5))
    int tot = 0;
    if (tid < 256) {
        #pragma unroll
        for (int r = 0; r < HPT; ++r) tot += hist[tid * HPT + r];
        suf[tid] = tot;
    }
    __syncthreads();
    for (int off = 1; off < 256; off <<= 1) {
        int add = 0;
        if (tid < 256 && tid + off < 256) add = suf[tid + off];
        __syncthreads();
        if (tid < 256) suf[tid] += add;
        __syncthreads();
    }
    // 3) threshold bin: largest bin j with count(>= bin j) >= DD
    if (tid < 256) {
        int cum = suf[tid] - tot;
        #pragma unroll
        for (int jj = HPT - 1; jj >= 0; --jj) {
            int j    = tid * HPT + jj;
            int prev = cum;
            cum += hist[j];
            if (cum >= DD && prev < DD) sh_tb = j;
        }
    }
    __syncthreads();
    const unsigned keyLo = ((unsigned)sh_tb + BIN0) << 15;

    // 4) gather all candidates with score bits >= keyLo (expected ~100-130)
    for (int i = tid; i < M; i += 1024) {
        ull key = kp[i];
        if ((unsigned)(key >> 32) >= keyLo) {
            int p = atomicAdd(&sh_cnt, 1);
            if (p < 512) { pk[p] = key; ps[p] = i; }
        }
    }
    __syncthreads();
    int ngath = sh_cnt; if (ngath > 512) ngath = 512;
    const int sortN = (ngath <= 128) ? 128 : (ngath <= 256) ? 256 : 512;
    for (int i = tid; i < sortN; i += 1024) { /* nothing: handled below */ }
    if (tid < sortN && tid >= ngath) { pk[tid] = 0ULL; ps[tid] = -1; }
    __syncthreads();

    // 5) bitonic sort desc by key (score, then lower flat idx)
    for (int k = 2; k <= sortN; k <<= 1) {
        for (int j = k >> 1; j > 0; j >>= 1) {
            if (tid < sortN) {
                int i = tid, ixj = i ^ j;
                if (ixj > i) {
                    bool desc = ((i & k) == 0);
                    ull a = pk[i], c = pk[ixj];
                    if (desc ? (a < c) : (a > c)) {
                        pk[i] = c; pk[ixj] = a;
                        int t = ps[i]; ps[i] = ps[ixj]; ps[ixj] = t;
                    }
                }
            }
            __syncthreads();
        }
    }

    // 6) emit top-100 (boxes re-decoded bit-identically)
    if (tid < DD) {
        float s; float4 bb; int label;
        if (tid < ngath) {
            ull key = pk[tid];
            unsigned fi   = ~(unsigned)(key & 0xFFFFFFFFu);
            unsigned meta = img_meta[(size_t)b * CAP + ps[tid]];
            unsigned r    = meta & 4095u;
            unsigned ci   = meta >> 12;
            s  = __uint_as_float((unsigned)(key >> 32));
            size_t n = (size_t)b * RR + r;
            const float4 pr = *(const float4*)(proposals + n * 4);
            const float4 rg = *(const float4*)(box_reg + n * 324 + (size_t)(ci + 1) * 4);
            bb = decode_box(pr, rg);
            label = (int)(fi / KK) + 1;
        } else {
            s = -1.0f; bb = make_float4(0.0f, 0.0f, 0.0f, 0.0f); label = 0;
        }
        out[(size_t)(b * DD + tid) * 4 + 0] = bb.x;
        out[(size_t)(b * DD + tid) * 4 + 1] = bb.y;
        out[(size_t)(b * DD + tid) * 4 + 2] = bb.z;
        out[(size_t)(b * DD + tid) * 4 + 3] = bb.w;
        out[(size_t)BB * DD * 4 + b * DD + tid] = s;
        out[(size_t)BB * DD * 4 + BB * DD + b * DD + tid] = (float)label;
    }
}

extern "C" void kernel_launch(void* const* d_in, const int* in_sizes, int n_in,
                              void* d_out, int out_size, void* d_ws, size_t ws_size,
                              hipStream_t stream) {
    const float* logits    = (const float*)d_in[0];   // [B*R, 81]
    const float* box_reg   = (const float*)d_in[1];   // [B*R, 324]
    const float* proposals = (const float*)d_in[2];   // [B*R, 4]
    float* out = (float*)d_out;

    char* ws = (char*)d_ws;
    int*      cls_cnt  = (int*)ws;                    //     5,120 B
    int*      g_cnt    = (int*)(ws + 5120);           //        64 B
    ull*      cand2    = (ull*)(ws + 5184);           // 5,242,880 B
    ull*      img_keys = (ull*)(ws + 5248064);        // 2,097,152 B
    unsigned* img_meta = (unsigned*)(ws + 7345216);   // 1,048,576 B

    hipMemsetAsync(ws, 0, 5184, stream);
    softmax_cand_kernel<<<(BB * RR) / 256, 256, 0, stream>>>(logits, cand2, cls_cnt);
    percls_kernel<<<(BB * NC) / TPB, 256, 0, stream>>>(cand2, cls_cnt, box_reg, proposals,
                                                       img_keys, img_meta, g_cnt);
    topd_kernel<<<BB, 1024, 0, stream>>>(img_keys, img_meta, g_cnt,
                                         box_reg, proposals, out);
}